// Round 7
// baseline (21171.587 us; speedup 1.0000x reference)
//
#include <hip/hip_runtime.h>

#define BATCH 64
#define TSEQ  4096
#define MROWS (BATCH * TSEQ)   // 262144
#define HD    256
#define G3    768

typedef unsigned short u16;
typedef unsigned int   u32;

__device__ __forceinline__ float bf2f(u16 x) {
  union { u32 u; float f; } v; v.u = ((u32)x) << 16; return v.f;
}
__device__ __forceinline__ u16 f2bf(float x) {
  union { float f; u32 u; } v; v.f = x;
  u32 r = (v.u + 0x7fffu + ((v.u >> 16) & 1u)) >> 16;
  return (u16)r;
}
__device__ __forceinline__ float lof(u32 p) {
  union { u32 u; float f; } v; v.u = p << 16; return v.f;
}
__device__ __forceinline__ float hif(u32 p) {
  union { u32 u; float f; } v; v.u = p & 0xffff0000u; return v.f;
}
__device__ __forceinline__ float fsig(float x) {
  float e = __expf(-x);
  return __builtin_amdgcn_rcpf(1.0f + e);
}
__device__ __forceinline__ float ftanh(float x) {
  float e = __expf(-2.0f * x);
  return 2.0f * __builtin_amdgcn_rcpf(1.0f + e) - 1.0f;
}

// ---- prep: WxT f32 [768][256], WhT bf16 [768][256], WoT f32 [256][256]; zero counter
__global__ __launch_bounds__(256) void k_prep(const float* __restrict__ Wx,
    const float* __restrict__ Wh, const float* __restrict__ Wo,
    float* __restrict__ WxT, u16* __restrict__ WhT, float* __restrict__ WoT,
    int* __restrict__ counter) {
  int idx = blockIdx.x * 256 + threadIdx.x;
  if (idx == 0) *counter = 0;
  if (idx < G3 * HD) {
    int n = idx >> 8, k = idx & 255;
    WxT[idx] = Wx[(size_t)k * G3 + n];
    WhT[idx] = f2bf(Wh[(size_t)k * G3 + n]);
  }
  if (idx < HD * HD) {
    int n = idx >> 8, k = idx & 255;
    WoT[idx] = Wo[(size_t)k * HD + n];
  }
}

// ---- segment discovery (validated R1-R2) ----
__global__ __launch_bounds__(256) void k_find_segs(const float* __restrict__ is_summ,
    u32* __restrict__ segs, int* __restrict__ counter) {
  int idx = blockIdx.x * 256 + threadIdx.x;
  if (idx >= MROWS) return;
  int b = idx >> 12, t = idx & 4095;
  bool start = (t == 0) || (is_summ[idx - 1] != 0.0f);
  if (!start) return;
  int tt = t;
  while (tt < 4095 && is_summ[(b << 12) + tt] == 0.0f) tt++;
  int L = tt - t + 1;
  int slot = atomicAdd(counter, 1);
  segs[slot] = (u32)idx | ((u32)L << 18);
}

// ---- VALU GEMM: C[M][N] = A_f32[M][256] * WT_f32[N][256]^T + bias
// block 64x64, thread tile 4x4. CBF: store bf16 (u16) else f32.
template<int N, bool CBF>
__global__ __launch_bounds__(256) void k_gemm_valu(const float* __restrict__ A,
    const float* __restrict__ WT, const float* __restrict__ bias,
    void* __restrict__ Cp) {
  constexpr int NB = N / 64;
  int bid = blockIdx.x;
  int nb = bid % NB, mb = bid / NB;
  int tid = threadIdx.x;
  int tm = (tid >> 4) * 4;
  int tn = (tid & 15) * 4;
  int m0 = mb * 64 + tm;
  int n0 = nb * 64 + tn;
  float acc[4][4] = {};
  for (int k = 0; k < HD; k += 4) {
    float a[4][4];
    #pragma unroll
    for (int i = 0; i < 4; i++) {
      float4 t = *(const float4*)(A + (size_t)(m0 + i) * HD + k);
      a[i][0] = t.x; a[i][1] = t.y; a[i][2] = t.z; a[i][3] = t.w;
    }
    #pragma unroll
    for (int j = 0; j < 4; j++) {
      float4 w = *(const float4*)(WT + (size_t)(n0 + j) * HD + k);
      #pragma unroll
      for (int i = 0; i < 4; i++)
        acc[i][j] += a[i][0] * w.x + a[i][1] * w.y + a[i][2] * w.z + a[i][3] * w.w;
    }
  }
  float b0 = bias[n0], b1 = bias[n0 + 1], b2 = bias[n0 + 2], b3 = bias[n0 + 3];
  #pragma unroll
  for (int i = 0; i < 4; i++) {
    if constexpr (CBF) {
      ushort4 o;
      o.x = f2bf(acc[i][0] + b0); o.y = f2bf(acc[i][1] + b1);
      o.z = f2bf(acc[i][2] + b2); o.w = f2bf(acc[i][3] + b3);
      *(ushort4*)((u16*)Cp + (size_t)(m0 + i) * N + n0) = o;
    } else {
      float4 o;
      o.x = acc[i][0] + b0; o.y = acc[i][1] + b1;
      o.z = acc[i][2] + b2; o.w = acc[i][3] + b3;
      *(float4*)((float*)Cp + (size_t)(m0 + i) * N + n0) = o;
    }
  }
}

// ---- segment-parallel GRU scan (logic validated: R2 == R3 bit-identical) ----
// h f32 in registers; h_all stored F32; h_last F32 into d_out.
__global__ __launch_bounds__(256) void k_scan(const u16* __restrict__ gx,
    const u16* __restrict__ WhT, const float* __restrict__ bh,
    const float* __restrict__ is_summ, float* __restrict__ h_all,
    float* __restrict__ h_last, const u32* __restrict__ segs,
    const int* __restrict__ pnseg) {
  int nseg = *pnseg;
  int lane = threadIdx.x & 63;
  int gwave = (blockIdx.x * 256 + threadIdx.x) >> 6;
  int nwaves = (gridDim.x * 256) >> 6;
  int d0 = lane * 4;

  float bhv[12];
  #pragma unroll
  for (int g = 0; g < 3; g++)
    #pragma unroll
    for (int q = 0; q < 4; q++)
      bhv[g * 4 + q] = bh[g * 256 + d0 + q];

  for (int s = gwave; s < nseg; s += nwaves) {
    u32 rec = segs[s];
    int gs = (int)(rec & 0x3FFFFu);
    int L = (int)(rec >> 18);
    float h[4] = {0.f, 0.f, 0.f, 0.f};
    for (int k = 0; k < L; k++) {
      int gidx = gs + k;
      float gh[12];
      #pragma unroll
      for (int j = 0; j < 12; j++) gh[j] = bhv[j];
      if (k != 0) {
        for (int c = 0; c < 32; c++) {
          float hv[8];
          #pragma unroll
          for (int e = 0; e < 8; e++)
            hv[e] = __shfl(h[e & 3], c * 2 + (e >> 2));
          #pragma unroll
          for (int g = 0; g < 3; g++) {
            #pragma unroll
            for (int q = 0; q < 4; q++) {
              const u16* wrow = WhT + (size_t)(g * 256 + d0 + q) * 256 + c * 8;
              uint4 wv = *(const uint4*)wrow;
              float a = gh[g * 4 + q];
              a += hv[0] * lof(wv.x) + hv[1] * hif(wv.x);
              a += hv[2] * lof(wv.y) + hv[3] * hif(wv.y);
              a += hv[4] * lof(wv.z) + hv[5] * hif(wv.z);
              a += hv[6] * lof(wv.w) + hv[7] * hif(wv.w);
              gh[g * 4 + q] = a;
            }
          }
        }
      }
      const u16* grow = gx + (size_t)gidx * G3 + d0;
      float gxv[12];
      #pragma unroll
      for (int g = 0; g < 3; g++) {
        ushort4 t4 = *(const ushort4*)(grow + g * 256);
        gxv[g * 4 + 0] = bf2f(t4.x);
        gxv[g * 4 + 1] = bf2f(t4.y);
        gxv[g * 4 + 2] = bf2f(t4.z);
        gxv[g * 4 + 3] = bf2f(t4.w);
      }
      float hn[4];
      #pragma unroll
      for (int q = 0; q < 4; q++) {
        float r = fsig(gxv[q] + gh[q]);
        float z = fsig(gxv[4 + q] + gh[4 + q]);
        float nn = ftanh(gxv[8 + q] + r * gh[8 + q]);
        hn[q] = (1.0f - z) * nn + z * h[q];
        h[q] = hn[q];
      }
      float4 st; st.x = hn[0]; st.y = hn[1]; st.z = hn[2]; st.w = hn[3];
      *(float4*)(h_all + (size_t)gidx * HD + d0) = st;
      if (k == L - 1 && ((gidx + 1) & 4095) == 0) {
        float m = 1.0f - is_summ[gidx];
        int b = gidx >> 12;
        float4 hl;
        hl.x = m * hn[0]; hl.y = m * hn[1]; hl.z = m * hn[2]; hl.w = m * hn[3];
        *(float4*)(h_last + (size_t)b * HD + d0) = hl;
      }
    }
  }
}

extern "C" void kernel_launch(void* const* d_in, const int* in_sizes, int n_in,
                              void* d_out, int out_size, void* d_ws, size_t ws_size,
                              hipStream_t stream) {
  const int exp_sizes[8] = {BATCH * TSEQ * HD, BATCH * TSEQ, HD * G3, HD * G3,
                            G3, G3, HD * HD, HD};
  if (n_in != 8) return;
  for (int i = 0; i < 8; i++)
    if (in_sizes[i] != exp_sizes[i]) return;

  const float* b_batch = (const float*)d_in[0];
  const float* is_summ = (const float*)d_in[1];
  const float* Wx = (const float*)d_in[2];
  const float* Wh = (const float*)d_in[3];
  const float* bx = (const float*)d_in[4];
  const float* bh = (const float*)d_in[5];
  const float* Wo = (const float*)d_in[6];
  const float* bo = (const float*)d_in[7];

  float* out = (float*)d_out;                      // *** f32 output (the fix) ***
  float* h_last = out + (size_t)MROWS * HD;

  char* ws = (char*)d_ws;
  size_t o = 0;
  u16*   gx   = (u16*)(ws + o);   o += (size_t)MROWS * G3 * 2;  // 402,653,184
  float* hall = (float*)(ws + o); o += (size_t)MROWS * HD * 4;  // 268,435,456
  float* WxT  = (float*)(ws + o); o += (size_t)G3 * HD * 4;
  u16*   WhT  = (u16*)(ws + o);   o += (size_t)G3 * HD * 2;
  float* WoT  = (float*)(ws + o); o += (size_t)HD * HD * 4;
  int*   counter = (int*)(ws + o); o += 256;
  u32*   segs = (u32*)(ws + o);   o += (size_t)MROWS * 4;
  if (ws_size < o) return;

  k_prep<<<768, 256, 0, stream>>>(Wx, Wh, Wo, WxT, WhT, WoT, counter);
  k_find_segs<<<MROWS / 256, 256, 0, stream>>>(is_summ, segs, counter);
  k_gemm_valu<G3, true><<<(MROWS / 64) * (G3 / 64), 256, 0, stream>>>(b_batch, WxT, bx, gx);
  k_scan<<<2048, 256, 0, stream>>>(gx, WhT, bh, is_summ, hall, h_last, segs, counter);
  k_gemm_valu<HD, false><<<(MROWS / 64) * (HD / 64), 256, 0, stream>>>(hall, WoT, bo, out);
}

// Round 8
// 4484.514 us; speedup vs baseline: 4.7210x; 4.7210x over previous
//
#include <hip/hip_runtime.h>

#define BATCH 64
#define TSEQ  4096
#define MROWS (BATCH * TSEQ)   // 262144
#define HD    256
#define G3    768
#define LCAP  64               // max segment length on the GEMM-step path
#define OVCAP 16384

typedef unsigned short u16;
typedef unsigned int   u32;
typedef __attribute__((ext_vector_type(8))) short bf16x8;
typedef __attribute__((ext_vector_type(4))) float f32x4;

__device__ __forceinline__ float bf2f(u16 x) {
  union { u32 u; float f; } v; v.u = ((u32)x) << 16; return v.f;
}
__device__ __forceinline__ u16 f2bf(float x) {
  union { float f; u32 u; } v; v.f = x;
  u32 r = (v.u + 0x7fffu + ((v.u >> 16) & 1u)) >> 16;
  return (u16)r;
}
__device__ __forceinline__ float lof(u32 p) {
  union { u32 u; float f; } v; v.u = p << 16; return v.f;
}
__device__ __forceinline__ float hif(u32 p) {
  union { u32 u; float f; } v; v.u = p & 0xffff0000u; return v.f;
}
__device__ __forceinline__ float fsig(float x) {
  float e = __expf(-x);
  return __builtin_amdgcn_rcpf(1.0f + e);
}
__device__ __forceinline__ float ftanh(float x) {
  float e = __expf(-2.0f * x);
  return 2.0f * __builtin_amdgcn_rcpf(1.0f + e) - 1.0f;
}
__device__ __forceinline__ bf16x8 pack8(float4 a, float4 b) {
  bf16x8 r;
  r[0] = (short)f2bf(a.x); r[1] = (short)f2bf(a.y);
  r[2] = (short)f2bf(a.z); r[3] = (short)f2bf(a.w);
  r[4] = (short)f2bf(b.x); r[5] = (short)f2bf(b.y);
  r[6] = (short)f2bf(b.z); r[7] = (short)f2bf(b.w);
  return r;
}

// meta (ints): [0]=c_tmp, [1]=c_over, [8+L]=cnt[L] L=1..64, [80+L]=cur[L], [160+k]=nact[k] k=0..63
#define M_CTMP 0
#define M_COVER 1
#define M_CNT 8
#define M_CUR 80
#define M_NACT 160

// ---- prep: weights -> bf16 transposed [N][K]; zero meta ----
__global__ __launch_bounds__(256) void k_prep(const float* __restrict__ Wx,
    const float* __restrict__ Wh, const float* __restrict__ Wo,
    u16* __restrict__ WxT, u16* __restrict__ WhT, u16* __restrict__ WoT,
    int* __restrict__ meta) {
  int idx = blockIdx.x * 256 + threadIdx.x;
  if (idx < 256) meta[idx] = 0;
  if (idx < G3 * HD) {
    int n = idx >> 8, k = idx & 255;
    WxT[idx] = f2bf(Wx[(size_t)k * G3 + n]);
    WhT[idx] = f2bf(Wh[(size_t)k * G3 + n]);
  }
  if (idx < HD * HD) {
    int n = idx >> 8, k = idx & 255;
    WoT[idx] = f2bf(Wo[(size_t)k * HD + n]);
  }
}

// ---- segment discovery + length histogram ----
__global__ __launch_bounds__(256) void k_find(const float* __restrict__ is_summ,
    u32* __restrict__ tmp, u32* __restrict__ over, int* __restrict__ meta) {
  int idx = blockIdx.x * 256 + threadIdx.x;
  if (idx >= MROWS) return;
  int b = idx >> 12, t = idx & 4095;
  bool start = (t == 0) || (is_summ[idx - 1] != 0.0f);
  if (!start) return;
  int tt = t;
  while (tt < 4095 && is_summ[(b << 12) + tt] == 0.0f) tt++;
  int L = tt - t + 1;
  if (L <= LCAP) {
    int slot = atomicAdd(&meta[M_CTMP], 1);
    tmp[slot] = (u32)idx | ((u32)L << 18);
    atomicAdd(&meta[M_CNT + L], 1);
  } else {
    int slot = atomicAdd(&meta[M_COVER], 1);
    if (slot < OVCAP) over[slot] = (u32)idx | ((u32)L << 18);
  }
}

// ---- bucket offsets (desc by L) + alive counts nact[k] ----
__global__ void k_buckets(int* __restrict__ meta) {
  if (threadIdx.x != 0) return;
  int acc = 0;
  for (int L = LCAP; L >= 1; --L) {
    meta[M_CUR + L] = acc;
    acc += meta[M_CNT + L];
    meta[M_NACT + (L - 1)] = acc;   // nact[k] = #segs with L > k
  }
}

// ---- scatter into length-desc sorted order ----
__global__ __launch_bounds__(256) void k_scatter(const u32* __restrict__ tmp,
    u32* __restrict__ sorted_gs, int* __restrict__ meta) {
  int n = meta[M_CTMP];
  int stride = gridDim.x * 256;
  for (int i = blockIdx.x * 256 + threadIdx.x; i < n; i += stride) {
    u32 rec = tmp[i];
    int L = (int)(rec >> 18);
    int slot = atomicAdd(&meta[M_CUR + L], 1);
    sorted_gs[slot] = rec & 0x3FFFFu;
  }
}

// ---- MFMA GEMM: C[M][N] = cvt_bf16(A_f32[M][256]) * BT_bf16[N][256]^T + bias ----
// 64x64 block tile, 4 waves x 16 rows, 4 n-subtiles each.
template<int N, bool STOREF32>
__global__ __launch_bounds__(256) void k_gemm_mfma(const float* __restrict__ A,
    const u16* __restrict__ BT, const float* __restrict__ bias,
    void* __restrict__ Cp) {
  constexpr int NB = N / 64;
  int bid = blockIdx.x;
  int nb = bid % NB, mb = bid / NB;
  int wv = threadIdx.x >> 6, lane = threadIdx.x & 63;
  int lr = lane & 15, lk = (lane >> 4) * 8;
  int m0 = mb * 64 + wv * 16;
  int n0 = nb * 64;
  const float* arow = A + (size_t)(m0 + lr) * HD + lk;
  f32x4 acc[4] = {{0,0,0,0},{0,0,0,0},{0,0,0,0},{0,0,0,0}};
  #pragma unroll
  for (int kk = 0; kk < 8; kk++) {
    float4 a0 = *(const float4*)(arow + kk * 32);
    float4 a1 = *(const float4*)(arow + kk * 32 + 4);
    bf16x8 av = pack8(a0, a1);
    #pragma unroll
    for (int ns = 0; ns < 4; ns++) {
      bf16x8 bv = *(const bf16x8*)(BT + (size_t)(n0 + ns * 16 + lr) * HD + kk * 32 + lk);
      acc[ns] = __builtin_amdgcn_mfma_f32_16x16x32_bf16(av, bv, acc[ns], 0, 0, 0);
    }
  }
  int r0 = m0 + (lane >> 4) * 4;
  #pragma unroll
  for (int ns = 0; ns < 4; ns++) {
    int col = n0 + ns * 16 + lr;
    float bv = bias[col];
    #pragma unroll
    for (int i = 0; i < 4; i++) {
      float v = acc[ns][i] + bv;
      if constexpr (STOREF32) ((float*)Cp)[(size_t)(r0 + i) * N + col] = v;
      else ((u16*)Cp)[(size_t)(r0 + i) * N + col] = f2bf(v);
    }
  }
}

// ---- step 0: h_prev = 0 for every sorted segment ----
__global__ __launch_bounds__(256) void k_step0(const u16* __restrict__ gx,
    const float* __restrict__ bh, const float* __restrict__ is_summ,
    float* __restrict__ hall, float* __restrict__ h_last,
    const u32* __restrict__ sorted_gs, const int* __restrict__ meta) {
  int nseg = meta[M_NACT + 0];
  long total = (long)nseg * 16;
  long stride = (long)gridDim.x * 256;
  for (long idx = blockIdx.x * 256 + threadIdx.x; idx < total; idx += stride) {
    int s = (int)(idx >> 4);
    int jb0 = ((int)idx & 15) * 16;
    int gidx = (int)sorted_gs[s];
    bool last_t = ((gidx + 1) & 4095) == 0;
    float m = last_t ? (1.0f - is_summ[gidx]) : 0.0f;
    const u16* grow = gx + (size_t)gidx * G3;
    #pragma unroll
    for (int ii = 0; ii < 4; ii++) {
      int jb = jb0 + ii * 4;
      ushort4 gr = *(const ushort4*)(grow + jb);
      ushort4 gz = *(const ushort4*)(grow + 256 + jb);
      ushort4 gn = *(const ushort4*)(grow + 512 + jb);
      float4 br = *(const float4*)(bh + jb);
      float4 bz = *(const float4*)(bh + 256 + jb);
      float4 bn = *(const float4*)(bh + 512 + jb);
      float hn[4];
      float gxr[4] = {bf2f(gr.x), bf2f(gr.y), bf2f(gr.z), bf2f(gr.w)};
      float gxz[4] = {bf2f(gz.x), bf2f(gz.y), bf2f(gz.z), bf2f(gz.w)};
      float gxn[4] = {bf2f(gn.x), bf2f(gn.y), bf2f(gn.z), bf2f(gn.w)};
      float bhr[4] = {br.x, br.y, br.z, br.w};
      float bhz[4] = {bz.x, bz.y, bz.z, bz.w};
      float bhn[4] = {bn.x, bn.y, bn.z, bn.w};
      #pragma unroll
      for (int i = 0; i < 4; i++) {
        float r = fsig(gxr[i] + bhr[i]);
        float z = fsig(gxz[i] + bhz[i]);
        float nn = ftanh(gxn[i] + r * bhn[i]);
        hn[i] = (1.0f - z) * nn;      // h_prev = 0
      }
      float4 st = {hn[0], hn[1], hn[2], hn[3]};
      *(float4*)(hall + (size_t)gidx * HD + jb) = st;
      if (last_t) {
        float4 hl = {m * hn[0], m * hn[1], m * hn[2], m * hn[3]};
        *(float4*)(h_last + (size_t)(gidx >> 12) * HD + jb) = hl;
      }
    }
  }
}

// ---- step k>=1: gh = h_prev @ Wh via MFMA (C^T orientation: A=WhT rows=n, B=h rows=segments) ----
// block = 64 segment-rows (4 waves x 16); wave loops 16 col-windows x 3 gate tiles.
__global__ __launch_bounds__(256) void k_stepN(const u16* __restrict__ gx,
    const u16* __restrict__ WhT, const float* __restrict__ bh,
    const float* __restrict__ is_summ, float* __restrict__ hall,
    float* __restrict__ h_last, const u32* __restrict__ sorted_gs,
    const int* __restrict__ meta, int k) {
  int nactk = meta[M_NACT + k];
  int wv = threadIdx.x >> 6, lane = threadIdx.x & 63;
  int sw = blockIdx.x * 64 + wv * 16;
  if (sw >= nactk) return;
  int c = lane & 15, g2 = lane >> 4;
  int srow = sw + c;
  bool alive = (srow < nactk);
  int sclamp = alive ? srow : (nactk - 1);
  int gs = (int)sorted_gs[sclamp];
  int gprev = gs + k - 1, gcur = gs + k;

  // B-fragments: h_prev row (f32) -> bf16, 8 K-chunks (lane holds k = kk*32 + g2*8 + j)
  bf16x8 bfr[8];
  const float* hp = hall + (size_t)gprev * HD + g2 * 8;
  #pragma unroll
  for (int kk = 0; kk < 8; kk++) {
    float4 u0 = *(const float4*)(hp + kk * 32);
    float4 u1 = *(const float4*)(hp + kk * 32 + 4);
    bfr[kk] = pack8(u0, u1);
  }

  bool last_t = ((gcur + 1) & 4095) == 0;
  float mlast = (alive && last_t) ? (1.0f - is_summ[gcur]) : 0.0f;

  for (int w = 0; w < 16; w++) {
    const u16* wr = WhT + (size_t)(w * 16 + c) * HD + g2 * 8;
    f32x4 ar = {0,0,0,0}, az = {0,0,0,0}, an = {0,0,0,0};
    #pragma unroll
    for (int kk = 0; kk < 8; kk++) {
      bf16x8 a0 = *(const bf16x8*)(wr + kk * 32);
      bf16x8 a1 = *(const bf16x8*)(wr + (size_t)256 * HD + kk * 32);
      bf16x8 a2 = *(const bf16x8*)(wr + (size_t)512 * HD + kk * 32);
      ar = __builtin_amdgcn_mfma_f32_16x16x32_bf16(a0, bfr[kk], ar, 0, 0, 0);
      az = __builtin_amdgcn_mfma_f32_16x16x32_bf16(a1, bfr[kk], az, 0, 0, 0);
      an = __builtin_amdgcn_mfma_f32_16x16x32_bf16(a2, bfr[kk], an, 0, 0, 0);
    }
    if (alive) {
      // D: col = c (segment), rows = n-offsets g2*4 + i within this window
      int jb = w * 16 + g2 * 4;
      const u16* grow = gx + (size_t)gcur * G3 + jb;
      ushort4 gr = *(const ushort4*)(grow);
      ushort4 gz = *(const ushort4*)(grow + 256);
      ushort4 gn = *(const ushort4*)(grow + 512);
      float4 hp4 = *(const float4*)(hall + (size_t)gprev * HD + jb);
      float4 br = *(const float4*)(bh + jb);
      float4 bz = *(const float4*)(bh + 256 + jb);
      float4 bn = *(const float4*)(bh + 512 + jb);
      float gxr[4] = {bf2f(gr.x), bf2f(gr.y), bf2f(gr.z), bf2f(gr.w)};
      float gxz[4] = {bf2f(gz.x), bf2f(gz.y), bf2f(gz.z), bf2f(gz.w)};
      float gxn[4] = {bf2f(gn.x), bf2f(gn.y), bf2f(gn.z), bf2f(gn.w)};
      float bhr[4] = {br.x, br.y, br.z, br.w};
      float bhz[4] = {bz.x, bz.y, bz.z, bz.w};
      float bhn[4] = {bn.x, bn.y, bn.z, bn.w};
      float hpv[4] = {hp4.x, hp4.y, hp4.z, hp4.w};
      float hn[4];
      #pragma unroll
      for (int i = 0; i < 4; i++) {
        float r = fsig(gxr[i] + ar[i] + bhr[i]);
        float z = fsig(gxz[i] + az[i] + bhz[i]);
        float nn = ftanh(gxn[i] + r * (an[i] + bhn[i]));
        hn[i] = (1.0f - z) * nn + z * hpv[i];
      }
      float4 st = {hn[0], hn[1], hn[2], hn[3]};
      *(float4*)(hall + (size_t)gcur * HD + jb) = st;
      if (last_t) {
        float4 hl = {mlast * hn[0], mlast * hn[1], mlast * hn[2], mlast * hn[3]};
        *(float4*)(h_last + (size_t)(gcur >> 12) * HD + jb) = hl;
      }
    }
  }
}

// ---- cleanup: segments with L > LCAP, sequential per wave (R7-validated k_scan) ----
__global__ __launch_bounds__(256) void k_cleanup(const u16* __restrict__ gx,
    const u16* __restrict__ WhT, const float* __restrict__ bh,
    const float* __restrict__ is_summ, float* __restrict__ h_all,
    float* __restrict__ h_last, const u32* __restrict__ over,
    const int* __restrict__ meta) {
  int nseg = meta[M_COVER];
  if (nseg > OVCAP) nseg = OVCAP;
  int lane = threadIdx.x & 63;
  int gwave = (blockIdx.x * 256 + threadIdx.x) >> 6;
  int nwaves = (gridDim.x * 256) >> 6;
  int d0 = lane * 4;
  float bhv[12];
  #pragma unroll
  for (int g = 0; g < 3; g++)
    #pragma unroll
    for (int q = 0; q < 4; q++)
      bhv[g * 4 + q] = bh[g * 256 + d0 + q];
  for (int s = gwave; s < nseg; s += nwaves) {
    u32 rec = over[s];
    int gs = (int)(rec & 0x3FFFFu);
    int L = (int)(rec >> 18);
    float h[4] = {0.f, 0.f, 0.f, 0.f};
    for (int k = 0; k < L; k++) {
      int gidx = gs + k;
      float gh[12];
      #pragma unroll
      for (int j = 0; j < 12; j++) gh[j] = bhv[j];
      if (k != 0) {
        for (int cc = 0; cc < 32; cc++) {
          float hv[8];
          #pragma unroll
          for (int e = 0; e < 8; e++)
            hv[e] = __shfl(h[e & 3], cc * 2 + (e >> 2));
          #pragma unroll
          for (int g = 0; g < 3; g++) {
            #pragma unroll
            for (int q = 0; q < 4; q++) {
              const u16* wrow = WhT + (size_t)(g * 256 + d0 + q) * 256 + cc * 8;
              uint4 wv = *(const uint4*)wrow;
              float a = gh[g * 4 + q];
              a += hv[0] * lof(wv.x) + hv[1] * hif(wv.x);
              a += hv[2] * lof(wv.y) + hv[3] * hif(wv.y);
              a += hv[4] * lof(wv.z) + hv[5] * hif(wv.z);
              a += hv[6] * lof(wv.w) + hv[7] * hif(wv.w);
              gh[g * 4 + q] = a;
            }
          }
        }
      }
      const u16* grow = gx + (size_t)gidx * G3 + d0;
      float gxv[12];
      #pragma unroll
      for (int g = 0; g < 3; g++) {
        ushort4 t4 = *(const ushort4*)(grow + g * 256);
        gxv[g * 4 + 0] = bf2f(t4.x);
        gxv[g * 4 + 1] = bf2f(t4.y);
        gxv[g * 4 + 2] = bf2f(t4.z);
        gxv[g * 4 + 3] = bf2f(t4.w);
      }
      float hn[4];
      #pragma unroll
      for (int q = 0; q < 4; q++) {
        float r = fsig(gxv[q] + gh[q]);
        float z = fsig(gxv[4 + q] + gh[4 + q]);
        float nn = ftanh(gxv[8 + q] + r * gh[8 + q]);
        hn[q] = (1.0f - z) * nn + z * h[q];
        h[q] = hn[q];
      }
      float4 st; st.x = hn[0]; st.y = hn[1]; st.z = hn[2]; st.w = hn[3];
      *(float4*)(h_all + (size_t)gidx * HD + d0) = st;
      if (k == L - 1 && ((gidx + 1) & 4095) == 0) {
        float m = 1.0f - is_summ[gidx];
        int b = gidx >> 12;
        float4 hl;
        hl.x = m * hn[0]; hl.y = m * hn[1]; hl.z = m * hn[2]; hl.w = m * hn[3];
        *(float4*)(h_last + (size_t)b * HD + d0) = hl;
      }
    }
  }
}

extern "C" void kernel_launch(void* const* d_in, const int* in_sizes, int n_in,
                              void* d_out, int out_size, void* d_ws, size_t ws_size,
                              hipStream_t stream) {
  const int exp_sizes[8] = {BATCH * TSEQ * HD, BATCH * TSEQ, HD * G3, HD * G3,
                            G3, G3, HD * HD, HD};
  if (n_in != 8) return;
  for (int i = 0; i < 8; i++)
    if (in_sizes[i] != exp_sizes[i]) return;

  const float* b_batch = (const float*)d_in[0];
  const float* is_summ = (const float*)d_in[1];
  const float* Wx = (const float*)d_in[2];
  const float* Wh = (const float*)d_in[3];
  const float* bx = (const float*)d_in[4];
  const float* bh = (const float*)d_in[5];
  const float* Wo = (const float*)d_in[6];
  const float* bo = (const float*)d_in[7];

  float* out = (float*)d_out;
  float* h_last = out + (size_t)MROWS * HD;

  char* ws = (char*)d_ws;
  size_t o = 0;
  u16*   gx   = (u16*)(ws + o);   o += (size_t)MROWS * G3 * 2;  // 402,653,184
  float* hall = (float*)(ws + o); o += (size_t)MROWS * HD * 4;  // 268,435,456
  u16*   WxT  = (u16*)(ws + o);   o += (size_t)G3 * HD * 2;
  u16*   WhT  = (u16*)(ws + o);   o += (size_t)G3 * HD * 2;
  u16*   WoT  = (u16*)(ws + o);   o += (size_t)HD * HD * 2;
  int*   meta = (int*)(ws + o);   o += 1024;
  u32*   tmp  = (u32*)(ws + o);   o += (size_t)MROWS * 4;
  u32*   sorted_gs = (u32*)(ws + o); o += (size_t)MROWS * 4;
  u32*   over = (u32*)(ws + o);   o += (size_t)OVCAP * 4;
  if (ws_size < o) return;

  k_prep<<<768, 256, 0, stream>>>(Wx, Wh, Wo, WxT, WhT, WoT, meta);
  k_find<<<MROWS / 256, 256, 0, stream>>>(is_summ, tmp, over, meta);
  k_buckets<<<1, 64, 0, stream>>>(meta);
  k_scatter<<<256, 256, 0, stream>>>(tmp, sorted_gs, meta);
  k_gemm_mfma<G3, false><<<(MROWS / 64) * (G3 / 64), 256, 0, stream>>>(b_batch, WxT, bx, gx);
  k_step0<<<2048, 256, 0, stream>>>(gx, bh, is_summ, hall, h_last, sorted_gs, meta);
  for (int k = 1; k < LCAP; k++) {
    int rows_ub = MROWS / (k + 1);
    int blocks = (rows_ub + 63) / 64;
    k_stepN<<<blocks, 256, 0, stream>>>(gx, WhT, bh, is_summ, hall, h_last,
                                        sorted_gs, meta, k);
  }
  k_cleanup<<<256, 256, 0, stream>>>(gx, WhT, bh, is_summ, hall, h_last, over, meta);
  k_gemm_mfma<HD, true><<<(MROWS / 64) * (HD / 64), 256, 0, stream>>>(hall, WoT, bo, out);
}

// Round 10
// 3781.507 us; speedup vs baseline: 5.5987x; 1.1859x over previous
//
#include <hip/hip_runtime.h>

#define BATCH 64
#define TSEQ  4096
#define MROWS (BATCH * TSEQ)   // 262144
#define HD    256
#define G3    768

typedef unsigned short u16;
typedef unsigned int   u32;
typedef __attribute__((ext_vector_type(8))) short bf16x8;
typedef __attribute__((ext_vector_type(4))) float f32x4;

__device__ __forceinline__ float bf2f(u16 x) {
  union { u32 u; float f; } v; v.u = ((u32)x) << 16; return v.f;
}
__device__ __forceinline__ u16 f2bf(float x) {
  union { float f; u32 u; } v; v.f = x;
  u32 r = (v.u + 0x7fffu + ((v.u >> 16) & 1u)) >> 16;
  return (u16)r;
}
__device__ __forceinline__ float fsig(float x) {
  float e = __expf(-x);
  return __builtin_amdgcn_rcpf(1.0f + e);
}
__device__ __forceinline__ float ftanh(float x) {
  float e = __expf(-2.0f * x);
  return 2.0f * __builtin_amdgcn_rcpf(1.0f + e) - 1.0f;
}
__device__ __forceinline__ bf16x8 pack8(float4 a, float4 b) {
  bf16x8 r;
  r[0] = (short)f2bf(a.x); r[1] = (short)f2bf(a.y);
  r[2] = (short)f2bf(a.z); r[3] = (short)f2bf(a.w);
  r[4] = (short)f2bf(b.x); r[5] = (short)f2bf(b.y);
  r[6] = (short)f2bf(b.z); r[7] = (short)f2bf(b.w);
  return r;
}

// meta ints: [0]=nseg, [8+L]=cnt (L=1..64, 64 holds L>=64), [80+L]=cur offsets
#define M_NSEG 0
#define M_CNT 8
#define M_CUR 80

// h LDS col swizzle: breaks stride-256 bank conflicts on A-fragment reads.
// XOR term is a multiple of 4 -> any 4-aligned float4 block stays contiguous;
// the address must be recomputed per float4 (NOT offset by +4 across blocks).
#define HCOL(r, c) ((c) ^ (((r) & 7) << 2))

// ---- prep: weights -> bf16 transposed [N][K]; zero meta ----
__global__ __launch_bounds__(256) void k_prep(const float* __restrict__ Wx,
    const float* __restrict__ Wh, const float* __restrict__ Wo,
    u16* __restrict__ WxT, u16* __restrict__ WhT, u16* __restrict__ WoT,
    int* __restrict__ meta) {
  int idx = blockIdx.x * 256 + threadIdx.x;
  if (idx < 256) meta[idx] = 0;
  if (idx < G3 * HD) {
    int n = idx >> 8, k = idx & 255;
    WxT[idx] = f2bf(Wx[(size_t)k * G3 + n]);
    WhT[idx] = f2bf(Wh[(size_t)k * G3 + n]);
  }
  if (idx < HD * HD) {
    int n = idx >> 8, k = idx & 255;
    WoT[idx] = f2bf(Wo[(size_t)k * HD + n]);
  }
}

// ---- segment discovery + length histogram (bucket = min(L,64)) ----
__global__ __launch_bounds__(256) void k_find(const float* __restrict__ is_summ,
    u32* __restrict__ tmp, int* __restrict__ meta) {
  int idx = blockIdx.x * 256 + threadIdx.x;
  if (idx >= MROWS) return;
  int b = idx >> 12, t = idx & 4095;
  bool start = (t == 0) || (is_summ[idx - 1] != 0.0f);
  if (!start) return;
  int tt = t;
  while (tt < 4095 && is_summ[(b << 12) + tt] == 0.0f) tt++;
  int L = tt - t + 1;
  int slot = atomicAdd(&meta[M_NSEG], 1);
  tmp[slot] = (u32)idx | ((u32)L << 18);
  int bk = L < 64 ? L : 64;
  atomicAdd(&meta[M_CNT + bk], 1);
}

// ---- bucket offsets (desc by L) ----
__global__ void k_buckets(int* __restrict__ meta) {
  if (threadIdx.x != 0) return;
  int acc = 0;
  for (int L = 64; L >= 1; --L) {
    meta[M_CUR + L] = acc;
    acc += meta[M_CNT + L];
  }
}

// ---- scatter into length-desc sorted order (full rec kept) ----
__global__ __launch_bounds__(256) void k_scatter(const u32* __restrict__ tmp,
    u32* __restrict__ sorted, int* __restrict__ meta) {
  int n = meta[M_NSEG];
  int stride = gridDim.x * 256;
  for (int i = blockIdx.x * 256 + threadIdx.x; i < n; i += stride) {
    u32 rec = tmp[i];
    int L = (int)(rec >> 18);
    int bk = L < 64 ? L : 64;
    int slot = atomicAdd(&meta[M_CUR + bk], 1);
    sorted[slot] = rec;
  }
}

// ---- MFMA GEMM: C[M][N] = bf16(A[M][256]) * BT_bf16[N][256]^T + bias ----
// 128x64 block tile, 4 waves x 32 rows (2 m-subtiles), B-frags shared.
// XCD-swizzled block order: same-mb group lands on one XCD's L2.
template<int N, bool ABF, bool STOREF32>
__global__ __launch_bounds__(256) void k_gemm(const void* __restrict__ Ap,
    const u16* __restrict__ BT, const float* __restrict__ bias,
    void* __restrict__ Cp) {
  constexpr int NB = N / 64;
  constexpr int NWG = (MROWS / 128) * NB;
  constexpr int CPX = NWG / 8;
  int bid = blockIdx.x;
  int wg = (bid & 7) * CPX + (bid >> 3);
  int mb = wg / NB, nb = wg % NB;
  int wv = threadIdx.x >> 6, lane = threadIdx.x & 63;
  int lr = lane & 15, lk = (lane >> 4) * 8;
  int m0 = mb * 128 + wv * 32;
  int n0 = nb * 64;
  const float* A32 = (const float*)Ap;
  const u16*   A16 = (const u16*)Ap;
  f32x4 acc[2][4] = {};
  #pragma unroll
  for (int kk = 0; kk < 8; kk++) {
    bf16x8 a0, a1;
    if constexpr (ABF) {
      a0 = *(const bf16x8*)(A16 + (size_t)(m0 + lr) * HD + kk * 32 + lk);
      a1 = *(const bf16x8*)(A16 + (size_t)(m0 + 16 + lr) * HD + kk * 32 + lk);
    } else {
      const float* r0p = A32 + (size_t)(m0 + lr) * HD + kk * 32 + lk;
      const float* r1p = A32 + (size_t)(m0 + 16 + lr) * HD + kk * 32 + lk;
      a0 = pack8(*(const float4*)r0p, *(const float4*)(r0p + 4));
      a1 = pack8(*(const float4*)r1p, *(const float4*)(r1p + 4));
    }
    #pragma unroll
    for (int ns = 0; ns < 4; ns++) {
      bf16x8 bv = *(const bf16x8*)(BT + (size_t)(n0 + ns * 16 + lr) * HD + kk * 32 + lk);
      acc[0][ns] = __builtin_amdgcn_mfma_f32_16x16x32_bf16(a0, bv, acc[0][ns], 0, 0, 0);
      acc[1][ns] = __builtin_amdgcn_mfma_f32_16x16x32_bf16(a1, bv, acc[1][ns], 0, 0, 0);
    }
  }
  #pragma unroll
  for (int mi = 0; mi < 2; mi++) {
    int r0 = m0 + mi * 16 + (lane >> 4) * 4;
    #pragma unroll
    for (int ns = 0; ns < 4; ns++) {
      int col = n0 + ns * 16 + lr;
      float bv = bias[col];
      #pragma unroll
      for (int i = 0; i < 4; i++) {
        float v = acc[mi][ns][i] + bv;
        if constexpr (STOREF32) ((float*)Cp)[(size_t)(r0 + i) * N + col] = v;
        else ((u16*)Cp)[(size_t)(r0 + i) * N + col] = f2bf(v);
      }
    }
  }
}

// ---- lockstep scan: ONE launch. Each wave owns 16 sorted segments, loops k. ----
// h in per-wave LDS f32 [16][256], XOR-swizzled cols. gh = h @ Wh via MFMA
// (A=h rows=segs, B=WhT rows=gate cols — convention validated in k_gemm).
__global__ __launch_bounds__(256) void k_scan2(const u16* __restrict__ gx,
    const u16* __restrict__ WhT, const float* __restrict__ bh,
    const float* __restrict__ is_summ, u16* __restrict__ hall,
    float* __restrict__ h_last, const u32* __restrict__ sorted,
    const int* __restrict__ meta) {
  __shared__ float hlds[4][16][256];
  int nseg = meta[M_NSEG];
  int wv = threadIdx.x >> 6, lane = threadIdx.x & 63;
  int unit = blockIdx.x * 4 + wv;
  int sbase = unit * 16;
  if (sbase >= nseg) return;
  float (*h)[256] = hlds[wv];
  int lr = lane & 15, g2 = lane >> 4;
  int lk = g2 * 8;

  // per-lane segment records (segs g2*4+i of this wave's 16)
  int gsv[4], Lv[4];
  #pragma unroll
  for (int i = 0; i < 4; i++) {
    int s = sbase + g2 * 4 + i;
    u32 rec = (s < nseg) ? sorted[s] : 0u;
    gsv[i] = (int)(rec & 0x3FFFFu);
    Lv[i]  = (s < nseg) ? (int)(rec >> 18) : 0;
  }
  int lm = max(max(Lv[0], Lv[1]), max(Lv[2], Lv[3]));
  #pragma unroll
  for (int off = 32; off; off >>= 1) lm = max(lm, __shfl_xor(lm, off));

  // ---- k = 0: h_prev = 0, gh = bh ----
  for (int w = 0; w < 16; w++) {
    int col = w * 16 + lr;
    float bhr = bh[col], bhz = bh[col + 256], bhn = bh[col + 512];
    #pragma unroll
    for (int i = 0; i < 4; i++) {
      int row = g2 * 4 + i;
      if (Lv[i] == 0) { h[row][HCOL(row, col)] = 0.0f; continue; }
      int gidx = gsv[i];
      float gr = bf2f(gx[(size_t)gidx * G3 + col]);
      float gz = bf2f(gx[(size_t)gidx * G3 + 256 + col]);
      float gn = bf2f(gx[(size_t)gidx * G3 + 512 + col]);
      float r = fsig(gr + bhr);
      float z = fsig(gz + bhz);
      float nn = ftanh(gn + r * bhn);
      float hnew = (1.0f - z) * nn;
      h[row][HCOL(row, col)] = hnew;
      hall[(size_t)gidx * HD + col] = f2bf(hnew);
      if (((gidx + 1) & 4095) == 0) {
        float m = 1.0f - is_summ[gidx];
        h_last[(size_t)(gidx >> 12) * HD + col] = m * hnew;
      }
    }
  }

  // ---- k >= 1 ----
  for (int k = 1; k < lm; k++) {
    // A-fragments from LDS (row = lr, logical k-cols kk*32+lk .. +7).
    // THE FIX: swizzled address computed PER float4 (c0+4 is wrong for odd lr).
    bf16x8 af[8];
    #pragma unroll
    for (int kk = 0; kk < 8; kk++) {
      float4 u0 = *(const float4*)&h[lr][HCOL(lr, kk * 32 + lk)];
      float4 u1 = *(const float4*)&h[lr][HCOL(lr, kk * 32 + lk + 4)];
      af[kk] = pack8(u0, u1);
    }
    for (int w = 0; w < 16; w++) {
      f32x4 ar = {0,0,0,0}, az = {0,0,0,0}, an = {0,0,0,0};
      const u16* wr = WhT + (size_t)(w * 16 + lr) * HD + lk;
      #pragma unroll
      for (int kk = 0; kk < 8; kk++) {
        bf16x8 b0 = *(const bf16x8*)(wr + kk * 32);
        bf16x8 b1 = *(const bf16x8*)(wr + (size_t)256 * HD + kk * 32);
        bf16x8 b2 = *(const bf16x8*)(wr + (size_t)512 * HD + kk * 32);
        ar = __builtin_amdgcn_mfma_f32_16x16x32_bf16(af[kk], b0, ar, 0, 0, 0);
        az = __builtin_amdgcn_mfma_f32_16x16x32_bf16(af[kk], b1, az, 0, 0, 0);
        an = __builtin_amdgcn_mfma_f32_16x16x32_bf16(af[kk], b2, an, 0, 0, 0);
      }
      int col = w * 16 + lr;
      float bhr = bh[col], bhz = bh[col + 256], bhn = bh[col + 512];
      #pragma unroll
      for (int i = 0; i < 4; i++) {
        if (k >= Lv[i]) continue;
        int row = g2 * 4 + i;
        int gidx = gsv[i] + k;
        float gr = bf2f(gx[(size_t)gidx * G3 + col]);
        float gz = bf2f(gx[(size_t)gidx * G3 + 256 + col]);
        float gn = bf2f(gx[(size_t)gidx * G3 + 512 + col]);
        float hp = h[row][HCOL(row, col)];
        float r = fsig(gr + ar[i] + bhr);
        float z = fsig(gz + az[i] + bhz);
        float nn = ftanh(gn + r * (an[i] + bhn));
        float hnew = (1.0f - z) * nn + z * hp;
        h[row][HCOL(row, col)] = hnew;
        hall[(size_t)gidx * HD + col] = f2bf(hnew);
        if (((gidx + 1) & 4095) == 0) {
          float m = 1.0f - is_summ[gidx];
          h_last[(size_t)(gidx >> 12) * HD + col] = m * hnew;
        }
      }
    }
  }
}

extern "C" void kernel_launch(void* const* d_in, const int* in_sizes, int n_in,
                              void* d_out, int out_size, void* d_ws, size_t ws_size,
                              hipStream_t stream) {
  const int exp_sizes[8] = {BATCH * TSEQ * HD, BATCH * TSEQ, HD * G3, HD * G3,
                            G3, G3, HD * HD, HD};
  if (n_in != 8) return;
  for (int i = 0; i < 8; i++)
    if (in_sizes[i] != exp_sizes[i]) return;

  const float* b_batch = (const float*)d_in[0];
  const float* is_summ = (const float*)d_in[1];
  const float* Wx = (const float*)d_in[2];
  const float* Wh = (const float*)d_in[3];
  const float* bx = (const float*)d_in[4];
  const float* bh = (const float*)d_in[5];
  const float* Wo = (const float*)d_in[6];
  const float* bo = (const float*)d_in[7];

  float* out = (float*)d_out;
  float* h_last = out + (size_t)MROWS * HD;

  char* ws = (char*)d_ws;
  size_t o = 0;
  u16* gx     = (u16*)(ws + o); o += (size_t)MROWS * G3 * 2;   // 402,653,184
  u16* hall   = (u16*)(ws + o); o += (size_t)MROWS * HD * 2;   // 134,217,728
  u16* WxT    = (u16*)(ws + o); o += (size_t)G3 * HD * 2;
  u16* WhT    = (u16*)(ws + o); o += (size_t)G3 * HD * 2;
  u16* WoT    = (u16*)(ws + o); o += (size_t)HD * HD * 2;
  int* meta   = (int*)(ws + o); o += 1024;
  u32* tmp    = (u32*)(ws + o); o += (size_t)MROWS * 4;
  u32* sorted = (u32*)(ws + o); o += (size_t)MROWS * 4;
  if (ws_size < o) return;

  k_prep<<<768, 256, 0, stream>>>(Wx, Wh, Wo, WxT, WhT, WoT, meta);
  k_find<<<MROWS / 256, 256, 0, stream>>>(is_summ, tmp, meta);
  k_buckets<<<1, 64, 0, stream>>>(meta);
  k_scatter<<<256, 256, 0, stream>>>(tmp, sorted, meta);
  k_gemm<G3, false, false><<<(MROWS / 128) * (G3 / 64), 256, 0, stream>>>(b_batch, WxT, bx, gx);
  k_scan2<<<MROWS / 64, 256, 0, stream>>>(gx, WhT, bh, is_summ, hall, h_last, sorted, meta);
  k_gemm<HD, true, true><<<(MROWS / 128) * (HD / 64), 256, 0, stream>>>(hall, WoT, bo, out);
}

// Round 11
// 3420.066 us; speedup vs baseline: 6.1904x; 1.1057x over previous
//
#include <hip/hip_runtime.h>

#define BATCH 64
#define TSEQ  4096
#define MROWS (BATCH * TSEQ)   // 262144
#define HD    256
#define G3    768

typedef unsigned short u16;
typedef unsigned int   u32;
typedef __attribute__((ext_vector_type(8))) short bf16x8;
typedef __attribute__((ext_vector_type(4))) float f32x4;

__device__ __forceinline__ float bf2f(u16 x) {
  union { u32 u; float f; } v; v.u = ((u32)x) << 16; return v.f;
}
__device__ __forceinline__ u16 f2bf(float x) {
  union { float f; u32 u; } v; v.f = x;
  u32 r = (v.u + 0x7fffu + ((v.u >> 16) & 1u)) >> 16;
  return (u16)r;
}
__device__ __forceinline__ float fsig(float x) {
  float e = __expf(-x);
  return __builtin_amdgcn_rcpf(1.0f + e);
}
__device__ __forceinline__ float ftanh(float x) {
  float e = __expf(-2.0f * x);
  return 2.0f * __builtin_amdgcn_rcpf(1.0f + e) - 1.0f;
}
__device__ __forceinline__ bf16x8 pack8(float4 a, float4 b) {
  bf16x8 r;
  r[0] = (short)f2bf(a.x); r[1] = (short)f2bf(a.y);
  r[2] = (short)f2bf(a.z); r[3] = (short)f2bf(a.w);
  r[4] = (short)f2bf(b.x); r[5] = (short)f2bf(b.y);
  r[6] = (short)f2bf(b.z); r[7] = (short)f2bf(b.w);
  return r;
}

#define M_NSEG 0
#define M_CNT 8
#define M_CUR 80

// h LDS col swizzle (validated R10): address computed PER float4.
#define HCOL(r, c) ((c) ^ (((r) & 7) << 2))

// ---- prep ----
__global__ __launch_bounds__(256) void k_prep(const float* __restrict__ Wx,
    const float* __restrict__ Wh, const float* __restrict__ Wo,
    u16* __restrict__ WxT, u16* __restrict__ WhT, u16* __restrict__ WoT,
    int* __restrict__ meta) {
  int idx = blockIdx.x * 256 + threadIdx.x;
  if (idx < 256) meta[idx] = 0;
  if (idx < G3 * HD) {
    int n = idx >> 8, k = idx & 255;
    WxT[idx] = f2bf(Wx[(size_t)k * G3 + n]);
    WhT[idx] = f2bf(Wh[(size_t)k * G3 + n]);
  }
  if (idx < HD * HD) {
    int n = idx >> 8, k = idx & 255;
    WoT[idx] = f2bf(Wo[(size_t)k * HD + n]);
  }
}

// ---- segment discovery + histogram ----
__global__ __launch_bounds__(256) void k_find(const float* __restrict__ is_summ,
    u32* __restrict__ tmp, int* __restrict__ meta) {
  int idx = blockIdx.x * 256 + threadIdx.x;
  if (idx >= MROWS) return;
  int b = idx >> 12, t = idx & 4095;
  bool start = (t == 0) || (is_summ[idx - 1] != 0.0f);
  if (!start) return;
  int tt = t;
  while (tt < 4095 && is_summ[(b << 12) + tt] == 0.0f) tt++;
  int L = tt - t + 1;
  int slot = atomicAdd(&meta[M_NSEG], 1);
  tmp[slot] = (u32)idx | ((u32)L << 18);
  int bk = L < 64 ? L : 64;
  atomicAdd(&meta[M_CNT + bk], 1);
}

__global__ void k_buckets(int* __restrict__ meta) {
  if (threadIdx.x != 0) return;
  int acc = 0;
  for (int L = 64; L >= 1; --L) {
    meta[M_CUR + L] = acc;
    acc += meta[M_CNT + L];
  }
}

__global__ __launch_bounds__(256) void k_scatter(const u32* __restrict__ tmp,
    u32* __restrict__ sorted, int* __restrict__ meta) {
  int n = meta[M_NSEG];
  int stride = gridDim.x * 256;
  for (int i = blockIdx.x * 256 + threadIdx.x; i < n; i += stride) {
    u32 rec = tmp[i];
    int L = (int)(rec >> 18);
    int bk = L < 64 ? L : 64;
    int slot = atomicAdd(&meta[M_CUR + bk], 1);
    sorted[slot] = rec;
  }
}

// ---- MFMA GEMM (validated R10): 128x64 tile, XCD swizzle ----
template<int N>
__global__ __launch_bounds__(256) void k_gemm(const float* __restrict__ A,
    const u16* __restrict__ BT, const float* __restrict__ bias,
    u16* __restrict__ C) {
  constexpr int NB = N / 64;
  constexpr int NWG = (MROWS / 128) * NB;
  constexpr int CPX = NWG / 8;
  int bid = blockIdx.x;
  int wg = (bid & 7) * CPX + (bid >> 3);
  int mb = wg / NB, nb = wg % NB;
  int wv = threadIdx.x >> 6, lane = threadIdx.x & 63;
  int lr = lane & 15, lk = (lane >> 4) * 8;
  int m0 = mb * 128 + wv * 32;
  int n0 = nb * 64;
  f32x4 acc[2][4] = {};
  #pragma unroll
  for (int kk = 0; kk < 8; kk++) {
    const float* r0p = A + (size_t)(m0 + lr) * HD + kk * 32 + lk;
    const float* r1p = A + (size_t)(m0 + 16 + lr) * HD + kk * 32 + lk;
    bf16x8 a0 = pack8(*(const float4*)r0p, *(const float4*)(r0p + 4));
    bf16x8 a1 = pack8(*(const float4*)r1p, *(const float4*)(r1p + 4));
    #pragma unroll
    for (int ns = 0; ns < 4; ns++) {
      bf16x8 bv = *(const bf16x8*)(BT + (size_t)(n0 + ns * 16 + lr) * HD + kk * 32 + lk);
      acc[0][ns] = __builtin_amdgcn_mfma_f32_16x16x32_bf16(a0, bv, acc[0][ns], 0, 0, 0);
      acc[1][ns] = __builtin_amdgcn_mfma_f32_16x16x32_bf16(a1, bv, acc[1][ns], 0, 0, 0);
    }
  }
  #pragma unroll
  for (int mi = 0; mi < 2; mi++) {
    int r0 = m0 + mi * 16 + (lane >> 4) * 4;
    #pragma unroll
    for (int ns = 0; ns < 4; ns++) {
      int col = n0 + ns * 16 + lr;
      float bv = bias[col];
      #pragma unroll
      for (int i = 0; i < 4; i++)
        C[(size_t)(r0 + i) * N + col] = f2bf(acc[mi][ns][i] + bv);
    }
  }
}

// ---- fused lockstep scan + out-GEMM. 128 threads = 2 waves, 16 segs each. ----
// h f32 [2][16][256] LDS (HCOL swizzle); Wh/Wo windows block-staged in sbuf
// (chunk-XOR swizzle: chunk c of row r stored at c^(r&7); read 2-way = free).
__global__ __launch_bounds__(128) void k_scan3(const u16* __restrict__ gx,
    const u16* __restrict__ WhT, const u16* __restrict__ WoT,
    const float* __restrict__ bh, const float* __restrict__ bo,
    const float* __restrict__ is_summ, float* __restrict__ out,
    float* __restrict__ h_last, const u32* __restrict__ sorted,
    const int* __restrict__ meta) {
  __shared__ float hlds[2][16][256];   // 32 KB
  __shared__ u16 sbuf[12288];          // 24 KB
  __shared__ int lmsh[2];
  int nseg = meta[M_NSEG];
  int tid = threadIdx.x;
  int wv = tid >> 6, lane = tid & 63;
  int lr = lane & 15, g2 = lane >> 4, lk = g2 * 8;
  int sbase = (blockIdx.x * 2 + wv) * 16;
  float (*h)[256] = hlds[wv];

  int gsv[4], Lv[4];
  #pragma unroll
  for (int i = 0; i < 4; i++) {
    int s = sbase + g2 * 4 + i;
    u32 rec = (s < nseg) ? sorted[s] : 0u;
    gsv[i] = (int)(rec & 0x3FFFFu);
    Lv[i]  = (s < nseg) ? (int)(rec >> 18) : 0;
  }
  int lm = max(max(Lv[0], Lv[1]), max(Lv[2], Lv[3]));
  #pragma unroll
  for (int off = 32; off; off >>= 1) lm = max(lm, __shfl_xor(lm, off));
  if (lane == 0) lmsh[wv] = lm;
  __syncthreads();
  int lmb = max(lmsh[0], lmsh[1]);
  if (lmb == 0) return;   // block-uniform

  bf16x8 af[8];

  for (int k = 0; k < lmb; k++) {
    bool act = (k < lm);   // wave-uniform
    if (k == 0) {
      // ---- k=0 update: h_prev = 0, gh = bh (no staging, no barriers) ----
      for (int w = 0; w < 16; w++) {
        int col = w * 16 + lr;
        float bhr = bh[col], bhz = bh[col + 256], bhn = bh[col + 512];
        #pragma unroll
        for (int i = 0; i < 4; i++) {
          int row = g2 * 4 + i;
          if (Lv[i] == 0) { h[row][HCOL(row, col)] = 0.0f; continue; }
          int gidx = gsv[i];
          float gr = bf2f(gx[(size_t)gidx * G3 + col]);
          float gz = bf2f(gx[(size_t)gidx * G3 + 256 + col]);
          float gn = bf2f(gx[(size_t)gidx * G3 + 512 + col]);
          float r = fsig(gr + bhr);
          float z = fsig(gz + bhz);
          float nn = ftanh(gn + r * bhn);
          float hnew = (1.0f - z) * nn;
          h[row][HCOL(row, col)] = hnew;
          if (((gidx + 1) & 4095) == 0) {
            float m = 1.0f - is_summ[gidx];
            h_last[(size_t)(gidx >> 12) * HD + col] = m * hnew;
          }
        }
      }
    } else {
      // ---- gh windows: stage Wh_w, MFMA, update ----
      for (int w = 0; w < 16; w++) {
        #pragma unroll
        for (int p = 0; p < 12; p++) {        // 1536 chunks / 128 threads
          int L = p * 128 + tid;
          int gate = L >> 9, rem = L & 511;
          int r = rem >> 5, c = rem & 31;
          *(uint4*)&sbuf[gate * 4096 + r * 256 + ((c ^ (r & 7)) * 8)] =
              *(const uint4*)&WhT[((size_t)(gate << 8) + w * 16 + r) * 256 + c * 8];
        }
        __syncthreads();
        if (act) {
          f32x4 ar = {0,0,0,0}, az = {0,0,0,0}, an = {0,0,0,0};
          #pragma unroll
          for (int kk = 0; kk < 8; kk++) {
            int ch = ((kk * 4 + g2) ^ (lr & 7)) * 8;
            bf16x8 b0 = *(const bf16x8*)&sbuf[lr * 256 + ch];
            bf16x8 b1 = *(const bf16x8*)&sbuf[4096 + lr * 256 + ch];
            bf16x8 b2 = *(const bf16x8*)&sbuf[8192 + lr * 256 + ch];
            ar = __builtin_amdgcn_mfma_f32_16x16x32_bf16(af[kk], b0, ar, 0, 0, 0);
            az = __builtin_amdgcn_mfma_f32_16x16x32_bf16(af[kk], b1, az, 0, 0, 0);
            an = __builtin_amdgcn_mfma_f32_16x16x32_bf16(af[kk], b2, an, 0, 0, 0);
          }
          int col = w * 16 + lr;
          float bhr = bh[col], bhz = bh[col + 256], bhn = bh[col + 512];
          #pragma unroll
          for (int i = 0; i < 4; i++) {
            if (k >= Lv[i]) continue;
            int row = g2 * 4 + i;
            int gidx = gsv[i] + k;
            float gr = bf2f(gx[(size_t)gidx * G3 + col]);
            float gz = bf2f(gx[(size_t)gidx * G3 + 256 + col]);
            float gn = bf2f(gx[(size_t)gidx * G3 + 512 + col]);
            float hp = h[row][HCOL(row, col)];
            float r = fsig(gr + ar[i] + bhr);
            float z = fsig(gz + az[i] + bhz);
            float nn = ftanh(gn + r * (an[i] + bhn));
            float hnew = (1.0f - z) * nn + z * hp;
            h[row][HCOL(row, col)] = hnew;
            if (((gidx + 1) & 4095) == 0) {
              float m = 1.0f - is_summ[gidx];
              h_last[(size_t)(gidx >> 12) * HD + col] = m * hnew;
            }
          }
        }
        __syncthreads();
      }
    }
    // ---- build A-fragments from updated h (per-float4 HCOL — validated) ----
    #pragma unroll
    for (int kk = 0; kk < 8; kk++) {
      float4 u0 = *(const float4*)&h[lr][HCOL(lr, kk * 32 + lk)];
      float4 u1 = *(const float4*)&h[lr][HCOL(lr, kk * 32 + lk + 4)];
      af[kk] = pack8(u0, u1);
    }
    // ---- out windows: stage Wo_w, MFMA, store r_out = h_new @ Wo + bo ----
    for (int w = 0; w < 16; w++) {
      #pragma unroll
      for (int p = 0; p < 4; p++) {          // 512 chunks / 128 threads
        int L = p * 128 + tid;
        int r = L >> 5, c = L & 31;
        *(uint4*)&sbuf[r * 256 + ((c ^ (r & 7)) * 8)] =
            *(const uint4*)&WoT[((size_t)w * 16 + r) * 256 + c * 8];
      }
      __syncthreads();
      if (act) {
        f32x4 ao = {0,0,0,0};
        #pragma unroll
        for (int kk = 0; kk < 8; kk++) {
          int ch = ((kk * 4 + g2) ^ (lr & 7)) * 8;
          bf16x8 bv = *(const bf16x8*)&sbuf[lr * 256 + ch];
          ao = __builtin_amdgcn_mfma_f32_16x16x32_bf16(af[kk], bv, ao, 0, 0, 0);
        }
        int col = w * 16 + lr;
        float bov = bo[col];
        #pragma unroll
        for (int i = 0; i < 4; i++) {
          if (k >= Lv[i]) continue;
          out[(size_t)(gsv[i] + k) * HD + col] = ao[i] + bov;
        }
      }
      __syncthreads();
    }
  }
}

extern "C" void kernel_launch(void* const* d_in, const int* in_sizes, int n_in,
                              void* d_out, int out_size, void* d_ws, size_t ws_size,
                              hipStream_t stream) {
  const int exp_sizes[8] = {BATCH * TSEQ * HD, BATCH * TSEQ, HD * G3, HD * G3,
                            G3, G3, HD * HD, HD};
  if (n_in != 8) return;
  for (int i = 0; i < 8; i++)
    if (in_sizes[i] != exp_sizes[i]) return;

  const float* b_batch = (const float*)d_in[0];
  const float* is_summ = (const float*)d_in[1];
  const float* Wx = (const float*)d_in[2];
  const float* Wh = (const float*)d_in[3];
  const float* bx = (const float*)d_in[4];
  const float* bh = (const float*)d_in[5];
  const float* Wo = (const float*)d_in[6];
  const float* bo = (const float*)d_in[7];

  float* out = (float*)d_out;
  float* h_last = out + (size_t)MROWS * HD;

  char* ws = (char*)d_ws;
  size_t o = 0;
  u16* gx     = (u16*)(ws + o); o += (size_t)MROWS * G3 * 2;   // 402,653,184
  u16* WxT    = (u16*)(ws + o); o += (size_t)G3 * HD * 2;
  u16* WhT    = (u16*)(ws + o); o += (size_t)G3 * HD * 2;
  u16* WoT    = (u16*)(ws + o); o += (size_t)HD * HD * 2;
  int* meta   = (int*)(ws + o); o += 1024;
  u32* tmp    = (u32*)(ws + o); o += (size_t)MROWS * 4;
  u32* sorted = (u32*)(ws + o); o += (size_t)MROWS * 4;
  if (ws_size < o) return;

  k_prep<<<768, 256, 0, stream>>>(Wx, Wh, Wo, WxT, WhT, WoT, meta);
  k_find<<<MROWS / 256, 256, 0, stream>>>(is_summ, tmp, meta);
  k_buckets<<<1, 64, 0, stream>>>(meta);
  k_scatter<<<256, 256, 0, stream>>>(tmp, sorted, meta);
  k_gemm<G3><<<(MROWS / 128) * (G3 / 64), 256, 0, stream>>>(b_batch, WxT, bx, gx);
  k_scan3<<<MROWS / 32, 128, 0, stream>>>(gx, WhT, WoT, bh, bo, is_summ,
                                          out, h_last, sorted, meta);
}